// Round 12
// baseline (769.891 us; speedup 1.0000x reference)
//
#include <hip/hip_runtime.h>

// ---------------------------------------------------------------------------
// UNet_old (graph U-Net, GMMConv K=10) on MI355X. fp32 in / fp32 out.
// R28-resubmit (R29): round 11 failed with GPUAcquisitionTimeout before any
// measurement -- identical source resubmitted to preserve attribution.
// R28: degree-sorted node scheduling for L4/L5 (straggler-variance attack).
// Phase-1 block time = max over 8 waves of Poisson-degree work (~35% waste,
// E[max8] ~ 10 vs mean 6.5 pair-iters). Fix: counting-sort nodes by degree
// (bins folded into k_scanall; scatter folded into k_scatter3 -- ZERO extra
// dispatches) and have k_aggf4 process perm[tile] while writing outputs to
// the ORIGINAL node rows. Bit-exact: same edges, same per-node accumulation
// order; only block->node assignment changes. Known cost: g5 gw reads lose
// streaming locality -> FETCH +10-20MB (the confirming counter signature).
// Everything else byte-identical to R27 (replicated 327us / L5 52.2 this
// container class). Falsified so far: R18 chunk-4 (FMA waste), R22 PIPE
// (VGPR/occupancy), R26 readlane-chunk (VALU/SGPR). Durable win: phase-2
// PF=8 B ring prefetch (R19).
// ---------------------------------------------------------------------------

#define N0C 65536
#define N1C 8192
#define N2C 1024
#define KK 10

typedef _Float16 half2t __attribute__((ext_vector_type(2)));
typedef _Float16 half4 __attribute__((ext_vector_type(4)));
typedef _Float16 f16x8 __attribute__((ext_vector_type(8)));
typedef float f32x4 __attribute__((ext_vector_type(4)));

static inline int cdiv(long long a, long long b) { return (int)((a + b - 1) / b); }

// fragment-tile index (in f16x8 units) for matrix row r, k-index kd.
__device__ __forceinline__ size_t fragi(int r, int kd, int KDT) {
    return ((size_t)(r >> 4) * KDT + (kd >> 5)) * 64 + ((kd >> 3) & 3) * 16 + (r & 15);
}

// ---------------- batched CSR build (3 graphs) ----------------

__global__ __launch_bounds__(256)
void k_hist3(const int* __restrict__ d1, const int* __restrict__ d2,
             const int* __restrict__ d3, int* __restrict__ g1,
             int* __restrict__ g2, int* __restrict__ g3,
             int E1, int E2, int E3) {
    int i = blockIdx.x * 256 + threadIdx.x;
    if (i < E1) atomicAdd(&g1[d1[i]], 1);
    else if (i < E1 + E2) atomicAdd(&g2[d2[i - E1]], 1);
    else if (i < E1 + E2 + E3) atomicAdd(&g3[d3[i - E1 - E2]], 1);
}

__device__ __forceinline__ void map_graph(int b, int& lb, int& gi) {
    if (b < 256) { gi = 0; lb = b; }
    else if (b < 288) { gi = 1; lb = b - 256; }
    else { gi = 2; lb = b - 288; }
}

// single-kernel scan: each block computes its global prefix base by
// redundantly summing deg[0 .. lb*256) (coalesced), then does the
// block-local scan and writes off/inv directly. Also builds the
// degree histogram bins for graphs 1,2 (perm counting sort).
__global__ __launch_bounds__(256)
void k_scanall(const int* __restrict__ deg1, int* __restrict__ off1, float* __restrict__ inv1,
               const int* __restrict__ deg2, int* __restrict__ off2, float* __restrict__ inv2,
               const int* __restrict__ deg3, int* __restrict__ off3, float* __restrict__ inv3,
               int* __restrict__ bins, int E1, int E2, int E3) {
    __shared__ int s[256];
    int lb, gi; map_graph(blockIdx.x, lb, gi);
    const int* deg = gi == 0 ? deg1 : (gi == 1 ? deg2 : deg3);
    int* off = gi == 0 ? off1 : (gi == 1 ? off2 : off3);
    float* inv = gi == 0 ? inv1 : (gi == 1 ? inv2 : inv3);
    int n = gi == 0 ? N0C : (gi == 1 ? N1C : N2C);
    int E = gi == 0 ? E1 : (gi == 1 ? E2 : E3);
    // redundant global-prefix sum
    int pre = 0;
    for (int i = threadIdx.x; i < lb * 256; i += 256) pre += deg[i];
    s[threadIdx.x] = pre;
    __syncthreads();
#pragma unroll
    for (int d = 128; d > 0; d >>= 1) {
        if (threadIdx.x < d) s[threadIdx.x] += s[threadIdx.x + d];
        __syncthreads();
    }
    int base = s[0];
    __syncthreads();
    // block-local inclusive scan
    int i = lb * 256 + threadIdx.x;
    int v = deg[i];
    // degree-bin histogram for the perm counting sort (graphs 1 and 2)
    if (gi == 0) atomicAdd(&bins[v < 63 ? v : 63], 1);
    else if (gi == 1) atomicAdd(&bins[64 + (v < 63 ? v : 63)], 1);
    s[threadIdx.x] = v;
    __syncthreads();
#pragma unroll
    for (int d = 1; d < 256; d <<= 1) {
        int t = (threadIdx.x >= d) ? s[threadIdx.x - d] : 0;
        __syncthreads();
        s[threadIdx.x] += t;
        __syncthreads();
    }
    off[i] = base + s[threadIdx.x] - v;
    inv[i] = 1.0f / fmaxf((float)v, 1.0f);
    if (i == n - 1) off[n] = E;
}

// Also builds perm1/perm2 (degree-sorted node order) -- bins are final
// since k_scanall completed before this dispatch.
__global__ __launch_bounds__(256)
void k_scatter3(const int* __restrict__ s1, const int* __restrict__ d1,
                const float* __restrict__ p1, const int* __restrict__ o1,
                int* __restrict__ c1, int* __restrict__ cs1, float2* __restrict__ cp1,
                const int* __restrict__ s2, const int* __restrict__ d2,
                const float* __restrict__ p2, const int* __restrict__ o2,
                int* __restrict__ c2, int* __restrict__ cs2, float2* __restrict__ cp2,
                const int* __restrict__ s3, const int* __restrict__ d3,
                const float* __restrict__ p3, const int* __restrict__ o3,
                int* __restrict__ c3, int* __restrict__ cs3, float2* __restrict__ cp3,
                const int* __restrict__ deg1, const int* __restrict__ deg2,
                int* __restrict__ bins, int* __restrict__ perm1, int* __restrict__ perm2,
                int E1, int E2, int E3) {
    int i = blockIdx.x * 256 + threadIdx.x;
    {
        const int* src; const int* dst; const float* pk; const int* off;
        int* cur; int* csrc; float2* cpk; int e; bool have = true;
        if (i < E1) { src = s1; dst = d1; pk = p1; off = o1; cur = c1; csrc = cs1; cpk = cp1; e = i; }
        else if (i < E1 + E2) { src = s2; dst = d2; pk = p2; off = o2; cur = c2; csrc = cs2; cpk = cp2; e = i - E1; }
        else if (i < E1 + E2 + E3) { src = s3; dst = d3; pk = p3; off = o3; cur = c3; csrc = cs3; cpk = cp3; e = i - E1 - E2; }
        else have = false;
        if (have) {
            int d = dst[e];
            int p = off[d] + atomicAdd(&cur[d], 1);
            csrc[p] = src[e];
            cpk[p] = reinterpret_cast<const float2*>(pk)[e];
        }
    }
    // perm build (counting-sort scatter); within-bin order nondeterministic,
    // which only permutes block->node assignment -- results bit-exact.
    if (i < N0C) {
        int d = deg1[i]; if (d > 63) d = 63;
        int boff = 0;
        for (int b = 0; b < d; ++b) boff += bins[b];
        int pos = boff + atomicAdd(&bins[128 + d], 1);
        perm1[pos] = i;
    }
    if (i < N1C) {
        int d = deg2[i]; if (d > 63) d = 63;
        int boff = 0;
        for (int b = 0; b < d; ++b) boff += bins[64 + b];
        int pos = boff + atomicAdd(&bins[192 + d], 1);
        perm2[pos] = i;
    }
}

// ---------------- batched gw precompute (5 layer-graph pairs) --------------
__global__ __launch_bounds__(256)
void k_gw(const float2* __restrict__ cp1, const float2* __restrict__ cp2,
          const float2* __restrict__ cp3,
          const float* __restrict__ mu1, const float* __restrict__ is1,
          const float* __restrict__ mu5, const float* __restrict__ is5,
          const float* __restrict__ mu2, const float* __restrict__ is2,
          const float* __restrict__ mu4, const float* __restrict__ is4,
          const float* __restrict__ mu3, const float* __restrict__ is3,
          float* __restrict__ g1, float* __restrict__ g5, float* __restrict__ g2,
          float* __restrict__ g4, float* __restrict__ g3,
          int E1, int E2, int E3) {
    int i = blockIdx.x * 256 + threadIdx.x;
    const float2* cp; const float* mu; const float* isg; float* g; int e;
    if (i < E1) { cp = cp1; mu = mu1; isg = is1; g = g1; e = i; }
    else if (i < 2 * E1) { cp = cp1; mu = mu5; isg = is5; g = g5; e = i - E1; }
    else if (i < 2 * E1 + E2) { cp = cp2; mu = mu2; isg = is2; g = g2; e = i - 2 * E1; }
    else if (i < 2 * E1 + 2 * E2) { cp = cp2; mu = mu4; isg = is4; g = g4; e = i - 2 * E1 - E2; }
    else if (i < 2 * E1 + 2 * E2 + E3) { cp = cp3; mu = mu3; isg = is3; g = g3; e = i - 2 * E1 - 2 * E2; }
    else return;
    float2 pk = cp[e];
    float o[KK];
#pragma unroll
    for (int k = 0; k < KK; ++k) {
        float dx = (pk.x - mu[2 * k]) * isg[2 * k];
        float dy = (pk.y - mu[2 * k + 1]) * isg[2 * k + 1];
        o[k] = __expf(-0.5f * (dx * dx + dy * dy));
    }
    float4* gp = reinterpret_cast<float4*>(g + (size_t)e * 12);
    gp[0] = make_float4(o[0], o[1], o[2], o[3]);
    gp[1] = make_float4(o[4], o[5], o[6], o[7]);
    gp[2] = make_float4(o[8], o[9], 0.f, 0.f);
}

// load 10 gaussian weights for edge j into existing array G[10]
#define LOAD_G2(gwp, j, G)                                                   \
    {                                                                        \
        const float4* gp_ = reinterpret_cast<const float4*>((gwp) + (size_t)(j) * 12); \
        float4 g0_ = gp_[0], g1_ = gp_[1];                                   \
        float2 g2_ = *reinterpret_cast<const float2*>(gp_ + 2);              \
        G[0] = g0_.x; G[1] = g0_.y; G[2] = g0_.z; G[3] = g0_.w;              \
        G[4] = g1_.x; G[5] = g1_.y; G[6] = g1_.z; G[7] = g1_.w;              \
        G[8] = g2_.x; G[9] = g2_.y;                                          \
    }

// ---------------- batched weight prep -> B-fragment tiles (+zeroing) -------
__global__ __launch_bounds__(256)
void k_prep_wt(const float* __restrict__ W1, const float* __restrict__ W2,
               const float* __restrict__ W3, const float* __restrict__ W4,
               const float* __restrict__ W5,
               _Float16* __restrict__ T2,
               _Float16* __restrict__ T3, _Float16* __restrict__ T4,
               _Float16* __restrict__ T5, int* __restrict__ degs, int degn,
               int* __restrict__ bins) {
    int id = blockIdx.x * 256 + threadIdx.x;
    if (id < degn) degs[id] = 0;          // replaces the hipMemsetAsync
    if (id < 256) bins[id] = 0;           // perm-sort bins + cursors
    if (id < 20480) {                      // Wt2: F=64, KD=320 (Cin=32)
        int f = id / 320, kc = id % 320;
        T2[fragi(f, kc, 10) * 8 + (kc & 7)] = (_Float16)W2[(kc % 32) * 640 + (kc / 32) * 64 + f];
        return;
    }
    id -= 20480;
    if (id < 81920) {                      // Wt3: F=128, KD=640 (Cin=64)
        int f = id / 640, kc = id % 640;
        T3[fragi(f, kc, 20) * 8 + (kc & 7)] = (_Float16)W3[(kc % 64) * 1280 + (kc / 64) * 128 + f];
        return;
    }
    id -= 81920;
    if (id < 122880) {                     // Wt4: F=64, KD=1920 (Cin=192)
        int f = id / 1920, kc = id % 1920;
        T4[fragi(f, kc, 60) * 8 + (kc & 7)] = (_Float16)W4[(kc % 192) * 640 + (kc / 192) * 64 + f];
        return;
    }
    id -= 122880;
    if (id < 46080) {                      // Wt5: F=48 (store 40), KD=960 (Cin=96)
        int f = id / 960, kc = id % 960;
        float v = (f < 40) ? W5[(kc % 96) * 400 + (kc / 96) * 40 + f] : 0.0f;
        T5[fragi(f, kc, 30) * 8 + (kc & 7)] = (_Float16)v;
    }
}

// ---------------- L1 fused: aggregate (Cin=2) + mini-GEMM + bias + relu
//                  + 8-node max-pool -> hp1. 2-way edge split/node
//                  (512 blocks -> 8 waves/CU), 1-deep prefetch loop. --------
__global__ __launch_bounds__(256, 3)
void k_l1(const float* __restrict__ x, const int* __restrict__ off,
          const int* __restrict__ csrc, const float* __restrict__ gw,
          const float* __restrict__ inv, const float* __restrict__ W1,
          const float* __restrict__ b1, _Float16* __restrict__ out0,
          _Float16* __restrict__ hp1) {
    __shared__ float Ws[640];
    __shared__ float bs[32];
    for (int i = threadIdx.x; i < 640; i += 256) Ws[i] = W1[i];
    if (threadIdx.x < 32) bs[threadIdx.x] = b1[threadIdx.x];
    __syncthreads();
    int tid2 = blockIdx.x * 256 + threadIdx.x;
    int n = tid2 >> 1;
    int h = tid2 & 1;
    float a0[KK], a1[KK];
#pragma unroll
    for (int k = 0; k < KK; ++k) { a0[k] = 0.f; a1[k] = 0.f; }
    int j0 = off[n], j1 = off[n + 1];
    // 1-deep prefetched edge loop, this thread handles edges j0+h, j0+h+2, ...
    int j = j0 + h;
    bool have = j < j1;
    float Gc[KK]; float2 xc;
    if (have) {
        int s = csrc[j];
        LOAD_G2(gw, j, Gc)
        xc = reinterpret_cast<const float2*>(x)[s];
    }
    while (have) {
        int jn = j + 2;
        bool hn = jn < j1;
        float Gn[KK]; float2 xn;
        if (hn) {
            int s = csrc[jn];
            LOAD_G2(gw, jn, Gn)
            xn = reinterpret_cast<const float2*>(x)[s];
        }
#pragma unroll
        for (int k = 0; k < KK; ++k) {
            a0[k] = fmaf(Gc[k], xc.x, a0[k]);
            a1[k] = fmaf(Gc[k], xc.y, a1[k]);
        }
        j = jn; have = hn;
        if (hn) {
#pragma unroll
            for (int k = 0; k < KK; ++k) Gc[k] = Gn[k];
            xc = xn;
        }
    }
    // combine the two edge-halves, scale by 1/deg
    float iv = inv[n];
#pragma unroll
    for (int k = 0; k < KK; ++k) {
        a0[k] = (a0[k] + __shfl_xor(a0[k], 1)) * iv;
        a1[k] = (a1[k] + __shfl_xor(a1[k], 1)) * iv;
    }
    _Float16* orow = out0 + (size_t)n * 32;
    _Float16* prow = hp1 + (size_t)(tid2 >> 4) * 32;
#pragma unroll
    for (int t = 0; t < 4; ++t) {
        int f4 = h * 4 + t;
        float v0 = bs[f4 * 4], v1 = bs[f4 * 4 + 1], v2 = bs[f4 * 4 + 2], v3 = bs[f4 * 4 + 3];
#pragma unroll
        for (int k = 0; k < KK; ++k) {
            const float* w0 = Ws + k * 32 + f4 * 4;
            const float* w1 = w0 + 320;
            v0 += a0[k] * w0[0] + a1[k] * w1[0];
            v1 += a0[k] * w0[1] + a1[k] * w1[1];
            v2 += a0[k] * w0[2] + a1[k] * w1[2];
            v3 += a0[k] * w0[3] + a1[k] * w1[3];
        }
        v0 = fmaxf(v0, 0.f); v1 = fmaxf(v1, 0.f);
        v2 = fmaxf(v2, 0.f); v3 = fmaxf(v3, 0.f);
        half4 o;
        o[0] = (_Float16)v0; o[1] = (_Float16)v1;
        o[2] = (_Float16)v2; o[3] = (_Float16)v3;
        *reinterpret_cast<half4*>(orow + f4 * 4) = o;
        // fused 8-node max-pool: 8 nodes = 16 threads; same-parity lanes at
        // distances 2,4,8 (all in-wave since 16 | 64).
#pragma unroll
        for (int d = 2; d < 16; d <<= 1) {
            v0 = fmaxf(v0, __shfl_xor(v0, d));
            v1 = fmaxf(v1, __shfl_xor(v1, d));
            v2 = fmaxf(v2, __shfl_xor(v2, d));
            v3 = fmaxf(v3, __shfl_xor(v3, d));
        }
        if ((threadIdx.x & 15) == h) {
            half4 p;
            p[0] = (_Float16)v0; p[1] = (_Float16)v1;
            p[2] = (_Float16)v2; p[3] = (_Float16)v3;
            *reinterpret_cast<half4*>(prow + f4 * 4) = p;
        }
    }
}

// ---------------- split aggregate-X (fp16 node-major src) ------------------
// TPN channel-threads x ES edge-split threads per node; 1-deep prefetched
// single-edge loop; shfl-combine across edge halves.
template <int TPN, int ES>
__global__ __launch_bounds__(256, 3)
void k_aggx(const _Float16* __restrict__ xp, const int* __restrict__ off,
            const int* __restrict__ csrc, const float* __restrict__ gw,
            const float* __restrict__ inv, _Float16* __restrict__ agg, int N) {
    constexpr int CIN = TPN * 4;
    constexpr int KDT = KK * CIN / 32;
    constexpr int TG = TPN * ES;
    int gtid = blockIdx.x * 256 + threadIdx.x;
    int node = gtid / TG;
    int rem = threadIdx.x % TG;
    int tt = rem % TPN, es = rem / TPN;
    if (node >= N) return;
    float a[KK][4];
#pragma unroll
    for (int k = 0; k < KK; ++k)
#pragma unroll
        for (int e = 0; e < 4; ++e) a[k][e] = 0.f;
    int j0 = off[node], j1 = off[node + 1];
    const _Float16* xb = xp + 4 * tt;
    int j = j0 + es;
    bool have = j < j1;
    float Gc[KK]; half4 hc;
    if (have) {
        int s = csrc[j];
        LOAD_G2(gw, j, Gc)
        hc = *reinterpret_cast<const half4*>(xb + (size_t)s * CIN);
    }
    while (have) {
        int jn = j + ES;
        bool hn = jn < j1;
        float Gn[KK]; half4 hx;
        if (hn) {
            int s = csrc[jn];
            LOAD_G2(gw, jn, Gn)
            hx = *reinterpret_cast<const half4*>(xb + (size_t)s * CIN);
        }
        float f0 = hc[0], f1 = hc[1], f2 = hc[2], f3 = hc[3];
#pragma unroll
        for (int k = 0; k < KK; ++k) {
            a[k][0] = fmaf(Gc[k], f0, a[k][0]);
            a[k][1] = fmaf(Gc[k], f1, a[k][1]);
            a[k][2] = fmaf(Gc[k], f2, a[k][2]);
            a[k][3] = fmaf(Gc[k], f3, a[k][3]);
        }
        j = jn; have = hn;
        if (hn) {
#pragma unroll
            for (int k = 0; k < KK; ++k) Gc[k] = Gn[k];
            hc = hx;
        }
    }
    // combine edge-splits (same tt, distances TPN, 2*TPN, ... in-wave)
#pragma unroll
    for (int d = TPN; d < TG; d <<= 1)
#pragma unroll
        for (int k = 0; k < KK; ++k) {
            a[k][0] += __shfl_xor(a[k][0], d);
            a[k][1] += __shfl_xor(a[k][1], d);
            a[k][2] += __shfl_xor(a[k][2], d);
            a[k][3] += __shfl_xor(a[k][3], d);
        }
    if (es == 0) {
        float iv = inv[node];
#pragma unroll
        for (int k = 0; k < KK; ++k) {
            half4 o;
            o[0] = (_Float16)(a[k][0] * iv); o[1] = (_Float16)(a[k][1] * iv);
            o[2] = (_Float16)(a[k][2] * iv); o[3] = (_Float16)(a[k][3] * iv);
            int kd = k * CIN + 4 * tt;
            *reinterpret_cast<half4*>(agg + fragi(node, kd, KDT) * 8 + (kd & 7)) = o;
        }
    }
}

// ---------------- L4/L5 fused aggregate + MFMA + act (k_aggf4) ------------
// Phase 1: wave-per-node gather over DEGREE-SORTED node order (perm):
// tile slot -> original node id via perm; lean even-pair loop + tail.
// Phase 2: waves wv<NT run the full-KDT MFMA chain; B (Wt) via PF=8-deep
// static ring prefetch issued BEFORE the barrier; outputs written to the
// ORIGINAL node rows (perm lookup per tile row).
template <int CA, int CB, int WPB, int NPW, int NT, int ACT, int FST, int OUTH>
__global__ __launch_bounds__(WPB * 64)
void k_aggf4(const _Float16* __restrict__ xA, const _Float16* __restrict__ xB,
             const int* __restrict__ off, const int* __restrict__ csrc,
             const float* __restrict__ gw, const float* __restrict__ inv,
             const _Float16* __restrict__ Wt, const float* __restrict__ bias,
             void* __restrict__ outv, const int* __restrict__ perm, int nodeBase) {
    constexpr int CIN = CA + CB;
    constexpr int PAIRS = CIN / 2;
    constexpr int P = (PAIRS + 63) / 64;
    constexpr int KDT = KK * CIN / 32;
    constexpr int STRIDE = KK * CIN + 8;
    __shared__ _Float16 lds[16 * STRIDE];
    const int lane = threadIdx.x & 63;
    const int wv = threadIdx.x >> 6;
    const int tilebase = nodeBase + blockIdx.x * 16;
    // hoisted CSR/adjacency preloads for all NPW nodes of this wave
    int j0u[NPW], degu[NPW], sallu[NPW], nodeu[NPW];
#pragma unroll
    for (int u = 0; u < NPW; ++u) {
        nodeu[u] = __builtin_amdgcn_readfirstlane(perm[tilebase + wv * NPW + u]);
        j0u[u] = __builtin_amdgcn_readfirstlane(off[nodeu[u]]);
        int j1 = __builtin_amdgcn_readfirstlane(off[nodeu[u] + 1]);
        degu[u] = j1 - j0u[u];
        int pl = (degu[u] > 0) ? (j0u[u] + (lane < degu[u] ? lane : degu[u] - 1)) : 0;
        sallu[u] = csrc[pl];
    }

#define AGG_FMA(GA, GB, XA0, XA1, XB0, XB1)                                   \
    _Pragma("unroll")                                                         \
    for (int k_ = 0; k_ < KK; ++k_)                                           \
        _Pragma("unroll")                                                     \
        for (int p_ = 0; p_ < P; ++p_) {                                      \
            a[k_][2 * p_] = fmaf(GA[k_], XA0[p_], a[k_][2 * p_]);             \
            a[k_][2 * p_ + 1] = fmaf(GA[k_], XA1[p_], a[k_][2 * p_ + 1]);     \
            a[k_][2 * p_] = fmaf(GB[k_], XB0[p_], a[k_][2 * p_]);             \
            a[k_][2 * p_ + 1] = fmaf(GB[k_], XB1[p_], a[k_][2 * p_ + 1]);     \
        }

#pragma unroll
    for (int u = 0; u < NPW; ++u) {
        const int nl = wv * NPW + u;
        const int j0 = j0u[u];
        const int deg = degu[u];
        const int sall = sallu[u];
        float a[KK][2 * P];
#pragma unroll
        for (int k = 0; k < KK; ++k)
#pragma unroll
            for (int p = 0; p < 2 * P; ++p) a[k][p] = 0.f;
        // ---- lean even-pair loop + 1-edge tail
        int e = 0;
        for (; e + 1 < deg; e += 2) {
            int sa = __builtin_amdgcn_readlane(sall, e);
            int sb = __builtin_amdgcn_readlane(sall, e + 1);
            int gj = __builtin_amdgcn_readfirstlane(j0 + e);
            float Ga[KK], Gb[KK];
            LOAD_G2(gw, gj, Ga)
            LOAD_G2(gw, gj + 1, Gb)
            float xa0[P], xa1[P], xb0[P], xb1[P];
#pragma unroll
            for (int p = 0; p < P; ++p) {
                int c0 = 2 * (lane + 64 * p);
                xa0[p] = 0.f; xa1[p] = 0.f; xb0[p] = 0.f; xb1[p] = 0.f;
                if (c0 < CIN) {
                    bool useA = c0 < CA;
                    const _Float16* qa = useA ? (xA + (size_t)(sa >> 3) * CA + c0)
                                              : (xB + (size_t)sa * CB + (c0 - CA));
                    const _Float16* qb = useA ? (xA + (size_t)(sb >> 3) * CA + c0)
                                              : (xB + (size_t)sb * CB + (c0 - CA));
                    half2t ha = *reinterpret_cast<const half2t*>(qa);
                    half2t hb = *reinterpret_cast<const half2t*>(qb);
                    xa0[p] = ha[0]; xa1[p] = ha[1];
                    xb0[p] = hb[0]; xb1[p] = hb[1];
                }
            }
            AGG_FMA(Ga, Gb, xa0, xa1, xb0, xb1)
        }
        if (e < deg) {
            int sa = __builtin_amdgcn_readlane(sall, e);
            int gj = __builtin_amdgcn_readfirstlane(j0 + e);
            float Ga[KK];
            LOAD_G2(gw, gj, Ga)
            float xa0[P], xa1[P];
#pragma unroll
            for (int p = 0; p < P; ++p) {
                int c0 = 2 * (lane + 64 * p);
                xa0[p] = 0.f; xa1[p] = 0.f;
                if (c0 < CIN) {
                    const _Float16* qa = (c0 < CA) ? (xA + (size_t)(sa >> 3) * CA + c0)
                                                   : (xB + (size_t)sa * CB + (c0 - CA));
                    half2t ha = *reinterpret_cast<const half2t*>(qa);
                    xa0[p] = ha[0]; xa1[p] = ha[1];
                }
            }
#pragma unroll
            for (int k = 0; k < KK; ++k)
#pragma unroll
                for (int p = 0; p < P; ++p) {
                    a[k][2 * p] = fmaf(Ga[k], xa0[p], a[k][2 * p]);
                    a[k][2 * p + 1] = fmaf(Ga[k], xa1[p], a[k][2 * p + 1]);
                }
        }
        float iv = inv[nodeu[u]];
#pragma unroll
        for (int k = 0; k < KK; ++k)
#pragma unroll
            for (int p = 0; p < P; ++p) {
                int c0 = 2 * (lane + 64 * p);
                if (c0 < CIN) {
                    half2t o;
                    o[0] = (_Float16)(a[k][2 * p] * iv);
                    o[1] = (_Float16)(a[k][2 * p + 1] * iv);
                    *reinterpret_cast<half2t*>(&lds[nl * STRIDE + k * CIN + c0]) = o;
                }
            }
    }
#undef AGG_FMA
    // ---- phase-2 B ring prefetch, issued before the barrier
    constexpr int PF = (KDT < 8) ? KDT : 8;
    const int lm = lane & 15;
    const int q = lane >> 4;
    const f16x8* bp = (const f16x8*)Wt + (size_t)wv * KDT * 64 + lane;
    f16x8 bfr[PF];
    if (wv < NT) {
#pragma unroll
        for (int i = 0; i < PF; ++i) bfr[i] = bp[(size_t)i * 64];
    }
    __syncthreads();
    // ---- phase 2: MFMA n-tile per wave (wv < NT), full KDT chain
    if (wv < NT) {
        f32x4 acc = (f32x4){0.f, 0.f, 0.f, 0.f};
        f16x8 af = *reinterpret_cast<const f16x8*>(&lds[lm * STRIDE + q * 8]);
#pragma unroll
        for (int i = 0; i < KDT; ++i) {
            f16x8 afn;
            if (i + 1 < KDT)
                afn = *reinterpret_cast<const f16x8*>(&lds[lm * STRIDE + (i + 1) * 32 + q * 8]);
            f16x8 b = bfr[i % PF];
            if (i + PF < KDT) bfr[i % PF] = bp[(size_t)(i + PF) * 64];
            acc = __builtin_amdgcn_mfma_f32_16x16x32_f16(af, b, acc, 0, 0, 0);
            af = afn;
        }
        int f = wv * 16 + lm;
        if (f < FST) {
            float b = bias ? bias[f] : 0.0f;
#pragma unroll
            for (int r = 0; r < 4; ++r) {
                size_t node = (size_t)perm[tilebase + q * 4 + r];
                float v = acc[r] + b;
                v = (ACT == 1) ? tanhf(v) : fmaxf(v, 0.0f);
                if (OUTH) ((_Float16*)outv)[node * FST + f] = (_Float16)v;
                else ((float*)outv)[node * FST + f] = v;
            }
        }
    }
}

// ---------------- pipelined MFMA GEMM (fragment-tile operands, L2/L3) ------
// POOL=1: additionally emit the 8-row max-pool of the activated output
// (fused k_pool8h; max commutes with monotonic fp16 rounding).
template <int WB, int NT, int ITERS, int ACT, int FST, int OUTH, int POOL>
__global__ __launch_bounds__(WB * 64)
void k_gemm2(const _Float16* __restrict__ A, const _Float16* __restrict__ B,
             const float* __restrict__ bias, void* __restrict__ outv,
             _Float16* __restrict__ poolout, int M) {
    constexpr int KDT = ITERS;
    const int lane = threadIdx.x & 63;
    const int wv = threadIdx.x >> 6;
    const int lm = lane & 15;
    const int q = lane >> 4;
    const size_t m0 = (size_t)blockIdx.y * (WB * 16) + wv * 16;
    const size_t mblk = m0 >> 4;
    f32x4 acc[NT];
#pragma unroll
    for (int t = 0; t < NT; ++t) acc[t] = (f32x4){0.f, 0.f, 0.f, 0.f};
    const f16x8* ap = (const f16x8*)A + mblk * KDT * 64 + lane;
    const f16x8* bp = (const f16x8*)B + lane;
    f16x8 af = ap[0];
    f16x8 bf[NT];
#pragma unroll
    for (int t = 0; t < NT; ++t) bf[t] = bp[(size_t)t * KDT * 64];
#pragma unroll
    for (int i = 0; i < ITERS; ++i) {
        f16x8 afn; f16x8 bfn[NT];
        if (i + 1 < ITERS) {
            afn = ap[(size_t)(i + 1) * 64];
#pragma unroll
            for (int t = 0; t < NT; ++t)
                bfn[t] = bp[((size_t)t * KDT + i + 1) * 64];
        }
#pragma unroll
        for (int t = 0; t < NT; ++t)
            acc[t] = __builtin_amdgcn_mfma_f32_16x16x32_f16(af, bf[t], acc[t], 0, 0, 0);
        af = afn;
#pragma unroll
        for (int t = 0; t < NT; ++t) bf[t] = bfn[t];
    }
#pragma unroll
    for (int t = 0; t < NT; ++t) {
        int f = t * 16 + lm;
        if (f < FST) {
            float b = bias ? bias[f] : 0.0f;
            float vr[4];
#pragma unroll
            for (int r = 0; r < 4; ++r) {
                float v = acc[t][r] + b;
                vr[r] = (ACT == 1) ? tanhf(v) : fmaxf(v, 0.0f);
            }
#pragma unroll
            for (int r = 0; r < 4; ++r) {
                if (OUTH) ((_Float16*)outv)[(m0 + q * 4 + r) * (size_t)FST + f] = (_Float16)vr[r];
                else ((float*)outv)[(m0 + q * 4 + r) * (size_t)FST + f] = vr[r];
            }
            if (POOL) {
                // rows q*4..q*4+3 in-lane; pair q with q^1 -> 8-row group max
                float m = fmaxf(fmaxf(vr[0], vr[1]), fmaxf(vr[2], vr[3]));
                m = fmaxf(m, __shfl_xor(m, 16));
                if ((q & 1) == 0)
                    poolout[(size_t)((m0 >> 3) + (q >> 1)) * FST + f] = (_Float16)m;
            }
        }
    }
}

extern "C" void kernel_launch(void* const* d_in, const int* in_sizes, int n_in,
                              void* d_out, int out_size, void* d_ws, size_t ws_size,
                              hipStream_t stream) {
    const float* n_feat = (const float*)d_in[0];
    const int* src1 = (const int*)d_in[1];
    const int* dst1 = (const int*)d_in[2];
    const float* pkor1 = (const float*)d_in[3];
    const int* src2 = (const int*)d_in[4];
    const int* dst2 = (const int*)d_in[5];
    const float* pkor2 = (const float*)d_in[6];
    const int* src3 = (const int*)d_in[7];
    const int* dst3 = (const int*)d_in[8];
    const float* pkor3 = (const float*)d_in[9];
    const float* W1 = (const float*)d_in[16];
    const float* mu1 = (const float*)d_in[17];
    const float* is1 = (const float*)d_in[18];
    const float* b1 = (const float*)d_in[19];
    const float* W2 = (const float*)d_in[20];
    const float* mu2 = (const float*)d_in[21];
    const float* is2 = (const float*)d_in[22];
    const float* W3 = (const float*)d_in[23];
    const float* mu3 = (const float*)d_in[24];
    const float* is3 = (const float*)d_in[25];
    const float* W4 = (const float*)d_in[26];
    const float* mu4 = (const float*)d_in[27];
    const float* is4 = (const float*)d_in[28];
    const float* W5 = (const float*)d_in[29];
    const float* mu5 = (const float*)d_in[30];
    const float* is5 = (const float*)d_in[31];
    const float* b5 = (const float*)d_in[32];

    const int E1 = in_sizes[1], E2 = in_sizes[4], E3 = in_sizes[7];
    const int NT_ = N0C + N1C + N2C;

    char* w = (char*)d_ws;
    auto alloc = [&](size_t bytes) {
        void* p = (void*)w;
        w += (bytes + 255) & ~(size_t)255;
        return p;
    };
    int* degs = (int*)alloc((size_t)NT_ * 2 * 4);
    int* deg1 = degs, *deg2 = degs + N0C, *deg3 = degs + N0C + N1C;
    int* cur1 = degs + NT_, *cur2 = cur1 + N0C, *cur3 = cur2 + N1C;
    int* bins = (int*)alloc(256 * 4);
    int* perm1 = (int*)alloc((size_t)N0C * 4);
    int* perm2 = (int*)alloc((size_t)N1C * 4);
    int* off1 = (int*)alloc(((size_t)N0C + 1) * 4);
    int* off2 = (int*)alloc(((size_t)N1C + 1) * 4);
    int* off3 = (int*)alloc(((size_t)N2C + 1) * 4);
    int* csrc1 = (int*)alloc((size_t)E1 * 4);
    float2* cpk1 = (float2*)alloc((size_t)E1 * 8);
    int* csrc2 = (int*)alloc((size_t)E2 * 4);
    float2* cpk2 = (float2*)alloc((size_t)E2 * 8);
    int* csrc3 = (int*)alloc((size_t)E3 * 4);
    float2* cpk3 = (float2*)alloc((size_t)E3 * 8);
    float* inv1 = (float*)alloc((size_t)N0C * 4);
    float* inv2 = (float*)alloc((size_t)N1C * 4);
    float* inv3 = (float*)alloc((size_t)N2C * 4);
    float* g1 = (float*)alloc(((size_t)2 * E1 + 2 * E2 + E3) * 12 * 4);
    float* g5 = g1 + (size_t)E1 * 12;
    float* g2 = g5 + (size_t)E1 * 12;
    float* g4 = g2 + (size_t)E2 * 12;
    float* g3 = g4 + (size_t)E2 * 12;
    _Float16* out0 = (_Float16*)alloc((size_t)N0C * 32 * 2);
    _Float16* out1 = (_Float16*)alloc((size_t)N1C * 64 * 2);
    _Float16* out2 = (_Float16*)alloc((size_t)N2C * 128 * 2);
    _Float16* out3 = (_Float16*)alloc((size_t)N1C * 64 * 2);
    _Float16* hp1 = (_Float16*)alloc((size_t)N1C * 32 * 2);
    _Float16* hp2 = (_Float16*)alloc((size_t)N2C * 64 * 2);
    _Float16* agg2 = (_Float16*)alloc((size_t)N1C * 320 * 2);
    _Float16* agg3 = (_Float16*)alloc((size_t)N2C * 640 * 2);
    _Float16* Wt2 = (_Float16*)alloc((size_t)64 * 320 * 2);
    _Float16* Wt3 = (_Float16*)alloc((size_t)128 * 640 * 2);
    _Float16* Wt4 = (_Float16*)alloc((size_t)64 * 1920 * 2);
    _Float16* Wt5 = (_Float16*)alloc((size_t)48 * 960 * 2);

    const int ET = E1 + E2 + E3;
    const int GT = 2 * E1 + 2 * E2 + E3;

    // ---- CSR build (batched) + weight prep + gw precompute
    k_prep_wt<<<cdiv(271360, 256), 256, 0, stream>>>(W1, W2, W3, W4, W5,
                                                     Wt2, Wt3, Wt4, Wt5,
                                                     degs, NT_ * 2, bins);
    k_hist3<<<cdiv(ET, 256), 256, 0, stream>>>(dst1, dst2, dst3, deg1, deg2, deg3, E1, E2, E3);
    k_scanall<<<292, 256, 0, stream>>>(deg1, off1, inv1, deg2, off2, inv2,
                                       deg3, off3, inv3, bins, E1, E2, E3);
    k_scatter3<<<cdiv(ET, 256), 256, 0, stream>>>(
        src1, dst1, pkor1, off1, cur1, csrc1, cpk1,
        src2, dst2, pkor2, off2, cur2, csrc2, cpk2,
        src3, dst3, pkor3, off3, cur3, csrc3, cpk3,
        deg1, deg2, bins, perm1, perm2, E1, E2, E3);
    k_gw<<<cdiv(GT, 256), 256, 0, stream>>>(
        cpk1, cpk2, cpk3, mu1, is1, mu5, is5, mu2, is2, mu4, is4, mu3, is3,
        g1, g5, g2, g4, g3, E1, E2, E3);

    // ---- L1 fused: aggregate + mini-GEMM + b1 + relu -> out0; pool -> hp1
    k_l1<<<N0C * 2 / 256, 256, 0, stream>>>(n_feat, off1, csrc1, g1, inv1, W1, b1, out0, hp1);

    // ---- L2: aggX (Cin=32, ES=2) -> agg2; GEMM+relu -> out1; fused pool -> hp2
    k_aggx<8, 2><<<cdiv((size_t)N1C * 16, 256), 256, 0, stream>>>(hp1, off2, csrc2, g2, inv2, agg2, N1C);
    k_gemm2<2, 4, 10, 0, 64, 1, 1><<<dim3(1, N1C / 32), 128, 0, stream>>>(agg2, Wt2, nullptr, out1, hp2, N1C);

    // ---- L3: aggX (Cin=64, ES=4) -> agg3; GEMM+relu -> out2 (N2,128) fp16
    k_aggx<16, 4><<<cdiv((size_t)N2C * 64, 256), 256, 0, stream>>>(hp2, off3, csrc3, g3, inv3, agg3, N2C);
    k_gemm2<1, 8, 20, 0, 128, 1, 0><<<dim3(1, N2C / 16), 64, 0, stream>>>(agg3, Wt3, nullptr, out2, nullptr, N2C);

    // ---- L4 fused: aggregate + MFMA (NT=4) + relu -> out3 (N1,64) fp16
    //      degree-sorted schedule via perm2
    k_aggf4<128, 64, 16, 1, 4, 0, 64, 1><<<N1C / 16, 1024, 0, stream>>>(
        out2, out1, off2, csrc2, g4, inv2, Wt4, nullptr, out3, perm2, 0);

    // ---- L5 fused: aggregate + MFMA (NT=3) + b5 + tanh -> d_out (N0,40) fp32
    //      degree-sorted schedule via perm1
    k_aggf4<64, 32, 8, 2, 3, 1, 40, 0><<<N0C / 16, 512, 0, stream>>>(
        out3, out0, off1, csrc1, g5, inv1, Wt5, b5, d_out, perm1, 0);
}

// Round 13
// 322.544 us; speedup vs baseline: 2.3869x; 2.3869x over previous
//
#include <hip/hip_runtime.h>

// ---------------------------------------------------------------------------
// UNet_old (graph U-Net, GMMConv K=10) on MI355X. fp32 in / fp32 out.
// R30 == R27 (final revert; session-converged configuration).
// R28 post-mortem: the degree-sort perm build died on atomic contention
// (k_scatter3 20us -> 266us: 65536 threads on ~13 bin counters); the
// straggler theory itself was never measurable under that foreground
// regression, and even full-success upside (~12us) is below the +-7%
// cross-container noise floor. Reverted.
// Session ledger:
//  - Durable win: L5 phase-2 PF=8 B ring prefetch (R19: L5 56->45us
//    fast-container; total 306->296).
//  - Neutral: dispatch fusions (scanall/prep_wt/pool-in-l1/pool-in-gemm2),
//    k_l1 2-way + aggx edge-splits.
//  - Falsified: R18 chunk-4 (FMA waste), R20 WPB4/NPW4 (occupancy),
//    R22 PIPE=1 (VGPR 32->52, occ 57->36%), R26 readlane-chunk (VALU+SGPR;
//    wave-uniform LOAD_G2 is a free s_load path), R28 degree-sort
//    (atomic contention).
//  - Structural floor: L5 = wave-serial edge chain at LDS-capped ~56% occ;
//    HBM 13% / VALU 42% / MFMA 4% -- latency-bound local optimum whose
//    remaining levers are under measurement noise.
// Harness-proven: 327.2us (preloaded:2 class) / 295.8us (fast class).
// ---------------------------------------------------------------------------

#define N0C 65536
#define N1C 8192
#define N2C 1024
#define KK 10

typedef _Float16 half2t __attribute__((ext_vector_type(2)));
typedef _Float16 half4 __attribute__((ext_vector_type(4)));
typedef _Float16 f16x8 __attribute__((ext_vector_type(8)));
typedef float f32x4 __attribute__((ext_vector_type(4)));

static inline int cdiv(long long a, long long b) { return (int)((a + b - 1) / b); }

// fragment-tile index (in f16x8 units) for matrix row r, k-index kd.
__device__ __forceinline__ size_t fragi(int r, int kd, int KDT) {
    return ((size_t)(r >> 4) * KDT + (kd >> 5)) * 64 + ((kd >> 3) & 3) * 16 + (r & 15);
}

// ---------------- batched CSR build (3 graphs) ----------------

__global__ __launch_bounds__(256)
void k_hist3(const int* __restrict__ d1, const int* __restrict__ d2,
             const int* __restrict__ d3, int* __restrict__ g1,
             int* __restrict__ g2, int* __restrict__ g3,
             int E1, int E2, int E3) {
    int i = blockIdx.x * 256 + threadIdx.x;
    if (i < E1) atomicAdd(&g1[d1[i]], 1);
    else if (i < E1 + E2) atomicAdd(&g2[d2[i - E1]], 1);
    else if (i < E1 + E2 + E3) atomicAdd(&g3[d3[i - E1 - E2]], 1);
}

__device__ __forceinline__ void map_graph(int b, int& lb, int& gi) {
    if (b < 256) { gi = 0; lb = b; }
    else if (b < 288) { gi = 1; lb = b - 256; }
    else { gi = 2; lb = b - 288; }
}

// single-kernel scan: each block computes its global prefix base by
// redundantly summing deg[0 .. lb*256) (coalesced), then does the
// block-local scan and writes off/inv directly.
__global__ __launch_bounds__(256)
void k_scanall(const int* __restrict__ deg1, int* __restrict__ off1, float* __restrict__ inv1,
               const int* __restrict__ deg2, int* __restrict__ off2, float* __restrict__ inv2,
               const int* __restrict__ deg3, int* __restrict__ off3, float* __restrict__ inv3,
               int E1, int E2, int E3) {
    __shared__ int s[256];
    int lb, gi; map_graph(blockIdx.x, lb, gi);
    const int* deg = gi == 0 ? deg1 : (gi == 1 ? deg2 : deg3);
    int* off = gi == 0 ? off1 : (gi == 1 ? off2 : off3);
    float* inv = gi == 0 ? inv1 : (gi == 1 ? inv2 : inv3);
    int n = gi == 0 ? N0C : (gi == 1 ? N1C : N2C);
    int E = gi == 0 ? E1 : (gi == 1 ? E2 : E3);
    // redundant global-prefix sum
    int pre = 0;
    for (int i = threadIdx.x; i < lb * 256; i += 256) pre += deg[i];
    s[threadIdx.x] = pre;
    __syncthreads();
#pragma unroll
    for (int d = 128; d > 0; d >>= 1) {
        if (threadIdx.x < d) s[threadIdx.x] += s[threadIdx.x + d];
        __syncthreads();
    }
    int base = s[0];
    __syncthreads();
    // block-local inclusive scan
    int i = lb * 256 + threadIdx.x;
    int v = deg[i];
    s[threadIdx.x] = v;
    __syncthreads();
#pragma unroll
    for (int d = 1; d < 256; d <<= 1) {
        int t = (threadIdx.x >= d) ? s[threadIdx.x - d] : 0;
        __syncthreads();
        s[threadIdx.x] += t;
        __syncthreads();
    }
    off[i] = base + s[threadIdx.x] - v;
    inv[i] = 1.0f / fmaxf((float)v, 1.0f);
    if (i == n - 1) off[n] = E;
}

__global__ __launch_bounds__(256)
void k_scatter3(const int* __restrict__ s1, const int* __restrict__ d1,
                const float* __restrict__ p1, const int* __restrict__ o1,
                int* __restrict__ c1, int* __restrict__ cs1, float2* __restrict__ cp1,
                const int* __restrict__ s2, const int* __restrict__ d2,
                const float* __restrict__ p2, const int* __restrict__ o2,
                int* __restrict__ c2, int* __restrict__ cs2, float2* __restrict__ cp2,
                const int* __restrict__ s3, const int* __restrict__ d3,
                const float* __restrict__ p3, const int* __restrict__ o3,
                int* __restrict__ c3, int* __restrict__ cs3, float2* __restrict__ cp3,
                int E1, int E2, int E3) {
    int i = blockIdx.x * 256 + threadIdx.x;
    const int* src; const int* dst; const float* pk; const int* off;
    int* cur; int* csrc; float2* cpk; int e;
    if (i < E1) { src = s1; dst = d1; pk = p1; off = o1; cur = c1; csrc = cs1; cpk = cp1; e = i; }
    else if (i < E1 + E2) { src = s2; dst = d2; pk = p2; off = o2; cur = c2; csrc = cs2; cpk = cp2; e = i - E1; }
    else if (i < E1 + E2 + E3) { src = s3; dst = d3; pk = p3; off = o3; cur = c3; csrc = cs3; cpk = cp3; e = i - E1 - E2; }
    else return;
    int d = dst[e];
    int p = off[d] + atomicAdd(&cur[d], 1);
    csrc[p] = src[e];
    cpk[p] = reinterpret_cast<const float2*>(pk)[e];
}

// ---------------- batched gw precompute (5 layer-graph pairs) --------------
__global__ __launch_bounds__(256)
void k_gw(const float2* __restrict__ cp1, const float2* __restrict__ cp2,
          const float2* __restrict__ cp3,
          const float* __restrict__ mu1, const float* __restrict__ is1,
          const float* __restrict__ mu5, const float* __restrict__ is5,
          const float* __restrict__ mu2, const float* __restrict__ is2,
          const float* __restrict__ mu4, const float* __restrict__ is4,
          const float* __restrict__ mu3, const float* __restrict__ is3,
          float* __restrict__ g1, float* __restrict__ g5, float* __restrict__ g2,
          float* __restrict__ g4, float* __restrict__ g3,
          int E1, int E2, int E3) {
    int i = blockIdx.x * 256 + threadIdx.x;
    const float2* cp; const float* mu; const float* isg; float* g; int e;
    if (i < E1) { cp = cp1; mu = mu1; isg = is1; g = g1; e = i; }
    else if (i < 2 * E1) { cp = cp1; mu = mu5; isg = is5; g = g5; e = i - E1; }
    else if (i < 2 * E1 + E2) { cp = cp2; mu = mu2; isg = is2; g = g2; e = i - 2 * E1; }
    else if (i < 2 * E1 + 2 * E2) { cp = cp2; mu = mu4; isg = is4; g = g4; e = i - 2 * E1 - E2; }
    else if (i < 2 * E1 + 2 * E2 + E3) { cp = cp3; mu = mu3; isg = is3; g = g3; e = i - 2 * E1 - 2 * E2; }
    else return;
    float2 pk = cp[e];
    float o[KK];
#pragma unroll
    for (int k = 0; k < KK; ++k) {
        float dx = (pk.x - mu[2 * k]) * isg[2 * k];
        float dy = (pk.y - mu[2 * k + 1]) * isg[2 * k + 1];
        o[k] = __expf(-0.5f * (dx * dx + dy * dy));
    }
    float4* gp = reinterpret_cast<float4*>(g + (size_t)e * 12);
    gp[0] = make_float4(o[0], o[1], o[2], o[3]);
    gp[1] = make_float4(o[4], o[5], o[6], o[7]);
    gp[2] = make_float4(o[8], o[9], 0.f, 0.f);
}

// load 10 gaussian weights for edge j into existing array G[10]
#define LOAD_G2(gwp, j, G)                                                   \
    {                                                                        \
        const float4* gp_ = reinterpret_cast<const float4*>((gwp) + (size_t)(j) * 12); \
        float4 g0_ = gp_[0], g1_ = gp_[1];                                   \
        float2 g2_ = *reinterpret_cast<const float2*>(gp_ + 2);              \
        G[0] = g0_.x; G[1] = g0_.y; G[2] = g0_.z; G[3] = g0_.w;              \
        G[4] = g1_.x; G[5] = g1_.y; G[6] = g1_.z; G[7] = g1_.w;              \
        G[8] = g2_.x; G[9] = g2_.y;                                          \
    }

// ---------------- batched weight prep -> B-fragment tiles (+deg zeroing) ---
__global__ __launch_bounds__(256)
void k_prep_wt(const float* __restrict__ W1, const float* __restrict__ W2,
               const float* __restrict__ W3, const float* __restrict__ W4,
               const float* __restrict__ W5,
               _Float16* __restrict__ T2,
               _Float16* __restrict__ T3, _Float16* __restrict__ T4,
               _Float16* __restrict__ T5, int* __restrict__ degs, int degn) {
    int id = blockIdx.x * 256 + threadIdx.x;
    if (id < degn) degs[id] = 0;          // replaces the hipMemsetAsync
    if (id < 20480) {                      // Wt2: F=64, KD=320 (Cin=32)
        int f = id / 320, kc = id % 320;
        T2[fragi(f, kc, 10) * 8 + (kc & 7)] = (_Float16)W2[(kc % 32) * 640 + (kc / 32) * 64 + f];
        return;
    }
    id -= 20480;
    if (id < 81920) {                      // Wt3: F=128, KD=640 (Cin=64)
        int f = id / 640, kc = id % 640;
        T3[fragi(f, kc, 20) * 8 + (kc & 7)] = (_Float16)W3[(kc % 64) * 1280 + (kc / 64) * 128 + f];
        return;
    }
    id -= 81920;
    if (id < 122880) {                     // Wt4: F=64, KD=1920 (Cin=192)
        int f = id / 1920, kc = id % 1920;
        T4[fragi(f, kc, 60) * 8 + (kc & 7)] = (_Float16)W4[(kc % 192) * 640 + (kc / 192) * 64 + f];
        return;
    }
    id -= 122880;
    if (id < 46080) {                      // Wt5: F=48 (store 40), KD=960 (Cin=96)
        int f = id / 960, kc = id % 960;
        float v = (f < 40) ? W5[(kc % 96) * 400 + (kc / 96) * 40 + f] : 0.0f;
        T5[fragi(f, kc, 30) * 8 + (kc & 7)] = (_Float16)v;
    }
}

// ---------------- L1 fused: aggregate (Cin=2) + mini-GEMM + bias + relu
//                  + 8-node max-pool -> hp1. 2-way edge split/node
//                  (512 blocks -> 8 waves/CU), 1-deep prefetch loop. --------
__global__ __launch_bounds__(256, 3)
void k_l1(const float* __restrict__ x, const int* __restrict__ off,
          const int* __restrict__ csrc, const float* __restrict__ gw,
          const float* __restrict__ inv, const float* __restrict__ W1,
          const float* __restrict__ b1, _Float16* __restrict__ out0,
          _Float16* __restrict__ hp1) {
    __shared__ float Ws[640];
    __shared__ float bs[32];
    for (int i = threadIdx.x; i < 640; i += 256) Ws[i] = W1[i];
    if (threadIdx.x < 32) bs[threadIdx.x] = b1[threadIdx.x];
    __syncthreads();
    int tid2 = blockIdx.x * 256 + threadIdx.x;
    int n = tid2 >> 1;
    int h = tid2 & 1;
    float a0[KK], a1[KK];
#pragma unroll
    for (int k = 0; k < KK; ++k) { a0[k] = 0.f; a1[k] = 0.f; }
    int j0 = off[n], j1 = off[n + 1];
    // 1-deep prefetched edge loop, this thread handles edges j0+h, j0+h+2, ...
    int j = j0 + h;
    bool have = j < j1;
    float Gc[KK]; float2 xc;
    if (have) {
        int s = csrc[j];
        LOAD_G2(gw, j, Gc)
        xc = reinterpret_cast<const float2*>(x)[s];
    }
    while (have) {
        int jn = j + 2;
        bool hn = jn < j1;
        float Gn[KK]; float2 xn;
        if (hn) {
            int s = csrc[jn];
            LOAD_G2(gw, jn, Gn)
            xn = reinterpret_cast<const float2*>(x)[s];
        }
#pragma unroll
        for (int k = 0; k < KK; ++k) {
            a0[k] = fmaf(Gc[k], xc.x, a0[k]);
            a1[k] = fmaf(Gc[k], xc.y, a1[k]);
        }
        j = jn; have = hn;
        if (hn) {
#pragma unroll
            for (int k = 0; k < KK; ++k) Gc[k] = Gn[k];
            xc = xn;
        }
    }
    // combine the two edge-halves, scale by 1/deg
    float iv = inv[n];
#pragma unroll
    for (int k = 0; k < KK; ++k) {
        a0[k] = (a0[k] + __shfl_xor(a0[k], 1)) * iv;
        a1[k] = (a1[k] + __shfl_xor(a1[k], 1)) * iv;
    }
    _Float16* orow = out0 + (size_t)n * 32;
    _Float16* prow = hp1 + (size_t)(tid2 >> 4) * 32;
#pragma unroll
    for (int t = 0; t < 4; ++t) {
        int f4 = h * 4 + t;
        float v0 = bs[f4 * 4], v1 = bs[f4 * 4 + 1], v2 = bs[f4 * 4 + 2], v3 = bs[f4 * 4 + 3];
#pragma unroll
        for (int k = 0; k < KK; ++k) {
            const float* w0 = Ws + k * 32 + f4 * 4;
            const float* w1 = w0 + 320;
            v0 += a0[k] * w0[0] + a1[k] * w1[0];
            v1 += a0[k] * w0[1] + a1[k] * w1[1];
            v2 += a0[k] * w0[2] + a1[k] * w1[2];
            v3 += a0[k] * w0[3] + a1[k] * w1[3];
        }
        v0 = fmaxf(v0, 0.f); v1 = fmaxf(v1, 0.f);
        v2 = fmaxf(v2, 0.f); v3 = fmaxf(v3, 0.f);
        half4 o;
        o[0] = (_Float16)v0; o[1] = (_Float16)v1;
        o[2] = (_Float16)v2; o[3] = (_Float16)v3;
        *reinterpret_cast<half4*>(orow + f4 * 4) = o;
        // fused 8-node max-pool: 8 nodes = 16 threads; same-parity lanes at
        // distances 2,4,8 (all in-wave since 16 | 64).
#pragma unroll
        for (int d = 2; d < 16; d <<= 1) {
            v0 = fmaxf(v0, __shfl_xor(v0, d));
            v1 = fmaxf(v1, __shfl_xor(v1, d));
            v2 = fmaxf(v2, __shfl_xor(v2, d));
            v3 = fmaxf(v3, __shfl_xor(v3, d));
        }
        if ((threadIdx.x & 15) == h) {
            half4 p;
            p[0] = (_Float16)v0; p[1] = (_Float16)v1;
            p[2] = (_Float16)v2; p[3] = (_Float16)v3;
            *reinterpret_cast<half4*>(prow + f4 * 4) = p;
        }
    }
}

// ---------------- split aggregate-X (fp16 node-major src) ------------------
// TPN channel-threads x ES edge-split threads per node; 1-deep prefetched
// single-edge loop; shfl-combine across edge halves.
template <int TPN, int ES>
__global__ __launch_bounds__(256, 3)
void k_aggx(const _Float16* __restrict__ xp, const int* __restrict__ off,
            const int* __restrict__ csrc, const float* __restrict__ gw,
            const float* __restrict__ inv, _Float16* __restrict__ agg, int N) {
    constexpr int CIN = TPN * 4;
    constexpr int KDT = KK * CIN / 32;
    constexpr int TG = TPN * ES;
    int gtid = blockIdx.x * 256 + threadIdx.x;
    int node = gtid / TG;
    int rem = threadIdx.x % TG;
    int tt = rem % TPN, es = rem / TPN;
    if (node >= N) return;
    float a[KK][4];
#pragma unroll
    for (int k = 0; k < KK; ++k)
#pragma unroll
        for (int e = 0; e < 4; ++e) a[k][e] = 0.f;
    int j0 = off[node], j1 = off[node + 1];
    const _Float16* xb = xp + 4 * tt;
    int j = j0 + es;
    bool have = j < j1;
    float Gc[KK]; half4 hc;
    if (have) {
        int s = csrc[j];
        LOAD_G2(gw, j, Gc)
        hc = *reinterpret_cast<const half4*>(xb + (size_t)s * CIN);
    }
    while (have) {
        int jn = j + ES;
        bool hn = jn < j1;
        float Gn[KK]; half4 hx;
        if (hn) {
            int s = csrc[jn];
            LOAD_G2(gw, jn, Gn)
            hx = *reinterpret_cast<const half4*>(xb + (size_t)s * CIN);
        }
        float f0 = hc[0], f1 = hc[1], f2 = hc[2], f3 = hc[3];
#pragma unroll
        for (int k = 0; k < KK; ++k) {
            a[k][0] = fmaf(Gc[k], f0, a[k][0]);
            a[k][1] = fmaf(Gc[k], f1, a[k][1]);
            a[k][2] = fmaf(Gc[k], f2, a[k][2]);
            a[k][3] = fmaf(Gc[k], f3, a[k][3]);
        }
        j = jn; have = hn;
        if (hn) {
#pragma unroll
            for (int k = 0; k < KK; ++k) Gc[k] = Gn[k];
            hc = hx;
        }
    }
    // combine edge-splits (same tt, distances TPN, 2*TPN, ... in-wave)
#pragma unroll
    for (int d = TPN; d < TG; d <<= 1)
#pragma unroll
        for (int k = 0; k < KK; ++k) {
            a[k][0] += __shfl_xor(a[k][0], d);
            a[k][1] += __shfl_xor(a[k][1], d);
            a[k][2] += __shfl_xor(a[k][2], d);
            a[k][3] += __shfl_xor(a[k][3], d);
        }
    if (es == 0) {
        float iv = inv[node];
#pragma unroll
        for (int k = 0; k < KK; ++k) {
            half4 o;
            o[0] = (_Float16)(a[k][0] * iv); o[1] = (_Float16)(a[k][1] * iv);
            o[2] = (_Float16)(a[k][2] * iv); o[3] = (_Float16)(a[k][3] * iv);
            int kd = k * CIN + 4 * tt;
            *reinterpret_cast<half4*>(agg + fragi(node, kd, KDT) * 8 + (kd & 7)) = o;
        }
    }
}

// ---------------- L4/L5 fused aggregate + MFMA + act (k_aggf4) ------------
// Phase 1: wave-per-node gather, lean even-pair mainloop + 1-edge tail.
// (All phase-1 restructures falsified: R18 chunk-4 = FMA waste, R22 PIPE =
// VGPR/occupancy, R26 readlane-chunk = VALU/SGPR, R28 degree-sort = atomic
// contention. Wave-uniform LOAD_G2 compiles to s_load -- free scalar path.)
// Phase 2: waves wv<NT run the full-KDT MFMA chain; B (Wt) via PF=8-deep
// static ring prefetch issued BEFORE the barrier (R19 win).
template <int CA, int CB, int WPB, int NPW, int NT, int ACT, int FST, int OUTH>
__global__ __launch_bounds__(WPB * 64)
void k_aggf4(const _Float16* __restrict__ xA, const _Float16* __restrict__ xB,
             const int* __restrict__ off, const int* __restrict__ csrc,
             const float* __restrict__ gw, const float* __restrict__ inv,
             const _Float16* __restrict__ Wt, const float* __restrict__ bias,
             void* __restrict__ outv, int nodeBase) {
    constexpr int CIN = CA + CB;
    constexpr int PAIRS = CIN / 2;
    constexpr int P = (PAIRS + 63) / 64;
    constexpr int KDT = KK * CIN / 32;
    constexpr int STRIDE = KK * CIN + 8;
    __shared__ _Float16 lds[16 * STRIDE];
    const int lane = threadIdx.x & 63;
    const int wv = threadIdx.x >> 6;
    // hoisted CSR/adjacency preloads for all NPW nodes of this wave
    int j0u[NPW], degu[NPW], sallu[NPW];
#pragma unroll
    for (int u = 0; u < NPW; ++u) {
        const int node = __builtin_amdgcn_readfirstlane(nodeBase + blockIdx.x * 16 + wv * NPW + u);
        j0u[u] = __builtin_amdgcn_readfirstlane(off[node]);
        int j1 = __builtin_amdgcn_readfirstlane(off[node + 1]);
        degu[u] = j1 - j0u[u];
        int pl = (degu[u] > 0) ? (j0u[u] + (lane < degu[u] ? lane : degu[u] - 1)) : 0;
        sallu[u] = csrc[pl];
    }

#define AGG_FMA(GA, GB, XA0, XA1, XB0, XB1)                                   \
    _Pragma("unroll")                                                         \
    for (int k_ = 0; k_ < KK; ++k_)                                           \
        _Pragma("unroll")                                                     \
        for (int p_ = 0; p_ < P; ++p_) {                                      \
            a[k_][2 * p_] = fmaf(GA[k_], XA0[p_], a[k_][2 * p_]);             \
            a[k_][2 * p_ + 1] = fmaf(GA[k_], XA1[p_], a[k_][2 * p_ + 1]);     \
            a[k_][2 * p_] = fmaf(GB[k_], XB0[p_], a[k_][2 * p_]);             \
            a[k_][2 * p_ + 1] = fmaf(GB[k_], XB1[p_], a[k_][2 * p_ + 1]);     \
        }

#pragma unroll
    for (int u = 0; u < NPW; ++u) {
        const int nl = wv * NPW + u;
        const int node = __builtin_amdgcn_readfirstlane(nodeBase + blockIdx.x * 16 + nl);
        const int j0 = j0u[u];
        const int deg = degu[u];
        const int sall = sallu[u];
        float a[KK][2 * P];
#pragma unroll
        for (int k = 0; k < KK; ++k)
#pragma unroll
            for (int p = 0; p < 2 * P; ++p) a[k][p] = 0.f;
        // ---- lean even-pair loop + 1-edge tail
        int e = 0;
        for (; e + 1 < deg; e += 2) {
            int sa = __builtin_amdgcn_readlane(sall, e);
            int sb = __builtin_amdgcn_readlane(sall, e + 1);
            int gj = __builtin_amdgcn_readfirstlane(j0 + e);
            float Ga[KK], Gb[KK];
            LOAD_G2(gw, gj, Ga)
            LOAD_G2(gw, gj + 1, Gb)
            float xa0[P], xa1[P], xb0[P], xb1[P];
#pragma unroll
            for (int p = 0; p < P; ++p) {
                int c0 = 2 * (lane + 64 * p);
                xa0[p] = 0.f; xa1[p] = 0.f; xb0[p] = 0.f; xb1[p] = 0.f;
                if (c0 < CIN) {
                    bool useA = c0 < CA;
                    const _Float16* qa = useA ? (xA + (size_t)(sa >> 3) * CA + c0)
                                              : (xB + (size_t)sa * CB + (c0 - CA));
                    const _Float16* qb = useA ? (xA + (size_t)(sb >> 3) * CA + c0)
                                              : (xB + (size_t)sb * CB + (c0 - CA));
                    half2t ha = *reinterpret_cast<const half2t*>(qa);
                    half2t hb = *reinterpret_cast<const half2t*>(qb);
                    xa0[p] = ha[0]; xa1[p] = ha[1];
                    xb0[p] = hb[0]; xb1[p] = hb[1];
                }
            }
            AGG_FMA(Ga, Gb, xa0, xa1, xb0, xb1)
        }
        if (e < deg) {
            int sa = __builtin_amdgcn_readlane(sall, e);
            int gj = __builtin_amdgcn_readfirstlane(j0 + e);
            float Ga[KK];
            LOAD_G2(gw, gj, Ga)
            float xa0[P], xa1[P];
#pragma unroll
            for (int p = 0; p < P; ++p) {
                int c0 = 2 * (lane + 64 * p);
                xa0[p] = 0.f; xa1[p] = 0.f;
                if (c0 < CIN) {
                    const _Float16* qa = (c0 < CA) ? (xA + (size_t)(sa >> 3) * CA + c0)
                                                   : (xB + (size_t)sa * CB + (c0 - CA));
                    half2t ha = *reinterpret_cast<const half2t*>(qa);
                    xa0[p] = ha[0]; xa1[p] = ha[1];
                }
            }
#pragma unroll
            for (int k = 0; k < KK; ++k)
#pragma unroll
                for (int p = 0; p < P; ++p) {
                    a[k][2 * p] = fmaf(Ga[k], xa0[p], a[k][2 * p]);
                    a[k][2 * p + 1] = fmaf(Ga[k], xa1[p], a[k][2 * p + 1]);
                }
        }
        float iv = inv[node];
#pragma unroll
        for (int k = 0; k < KK; ++k)
#pragma unroll
            for (int p = 0; p < P; ++p) {
                int c0 = 2 * (lane + 64 * p);
                if (c0 < CIN) {
                    half2t o;
                    o[0] = (_Float16)(a[k][2 * p] * iv);
                    o[1] = (_Float16)(a[k][2 * p + 1] * iv);
                    *reinterpret_cast<half2t*>(&lds[nl * STRIDE + k * CIN + c0]) = o;
                }
            }
    }
#undef AGG_FMA
    // ---- phase-2 B ring prefetch, issued before the barrier
    constexpr int PF = (KDT < 8) ? KDT : 8;
    const int lm = lane & 15;
    const int q = lane >> 4;
    const f16x8* bp = (const f16x8*)Wt + (size_t)wv * KDT * 64 + lane;
    f16x8 bfr[PF];
    if (wv < NT) {
#pragma unroll
        for (int i = 0; i < PF; ++i) bfr[i] = bp[(size_t)i * 64];
    }
    __syncthreads();
    // ---- phase 2: MFMA n-tile per wave (wv < NT), full KDT chain
    if (wv < NT) {
        f32x4 acc = (f32x4){0.f, 0.f, 0.f, 0.f};
        f16x8 af = *reinterpret_cast<const f16x8*>(&lds[lm * STRIDE + q * 8]);
#pragma unroll
        for (int i = 0; i < KDT; ++i) {
            f16x8 afn;
            if (i + 1 < KDT)
                afn = *reinterpret_cast<const f16x8*>(&lds[lm * STRIDE + (i + 1) * 32 + q * 8]);
            f16x8 b = bfr[i % PF];
            if (i + PF < KDT) bfr[i % PF] = bp[(size_t)(i + PF) * 64];
            acc = __builtin_amdgcn_mfma_f32_16x16x32_f16(af, b, acc, 0, 0, 0);
            af = afn;
        }
        int f = wv * 16 + lm;
        if (f < FST) {
            float b = bias ? bias[f] : 0.0f;
#pragma unroll
            for (int r = 0; r < 4; ++r) {
                size_t node = (size_t)nodeBase + (size_t)blockIdx.x * 16 + q * 4 + r;
                float v = acc[r] + b;
                v = (ACT == 1) ? tanhf(v) : fmaxf(v, 0.0f);
                if (OUTH) ((_Float16*)outv)[node * FST + f] = (_Float16)v;
                else ((float*)outv)[node * FST + f] = v;
            }
        }
    }
}

// ---------------- pipelined MFMA GEMM (fragment-tile operands, L2/L3) ------
// POOL=1: additionally emit the 8-row max-pool of the activated output
// (fused k_pool8h; max commutes with monotonic fp16 rounding).
template <int WB, int NT, int ITERS, int ACT, int FST, int OUTH, int POOL>
__global__ __launch_bounds__(WB * 64)
void k_gemm2(const _Float16* __restrict__ A, const _Float16* __restrict__ B,
             const float* __restrict__ bias, void* __restrict__ outv,
             _Float16* __restrict__ poolout, int M) {
    constexpr int KDT = ITERS;
    const int lane = threadIdx.x & 63;
    const int wv = threadIdx.x >> 6;
    const int lm = lane & 15;
    const int q = lane >> 4;
    const size_t m0 = (size_t)blockIdx.y * (WB * 16) + wv * 16;
    const size_t mblk = m0 >> 4;
    f32x4 acc[NT];
#pragma unroll
    for (int t = 0; t < NT; ++t) acc[t] = (f32x4){0.f, 0.f, 0.f, 0.f};
    const f16x8* ap = (const f16x8*)A + mblk * KDT * 64 + lane;
    const f16x8* bp = (const f16x8*)B + lane;
    f16x8 af = ap[0];
    f16x8 bf[NT];
#pragma unroll
    for (int t = 0; t < NT; ++t) bf[t] = bp[(size_t)t * KDT * 64];
#pragma unroll
    for (int i = 0; i < ITERS; ++i) {
        f16x8 afn; f16x8 bfn[NT];
        if (i + 1 < ITERS) {
            afn = ap[(size_t)(i + 1) * 64];
#pragma unroll
            for (int t = 0; t < NT; ++t)
                bfn[t] = bp[((size_t)t * KDT + i + 1) * 64];
        }
#pragma unroll
        for (int t = 0; t < NT; ++t)
            acc[t] = __builtin_amdgcn_mfma_f32_16x16x32_f16(af, bf[t], acc[t], 0, 0, 0);
        af = afn;
#pragma unroll
        for (int t = 0; t < NT; ++t) bf[t] = bfn[t];
    }
#pragma unroll
    for (int t = 0; t < NT; ++t) {
        int f = t * 16 + lm;
        if (f < FST) {
            float b = bias ? bias[f] : 0.0f;
            float vr[4];
#pragma unroll
            for (int r = 0; r < 4; ++r) {
                float v = acc[t][r] + b;
                vr[r] = (ACT == 1) ? tanhf(v) : fmaxf(v, 0.0f);
            }
#pragma unroll
            for (int r = 0; r < 4; ++r) {
                if (OUTH) ((_Float16*)outv)[(m0 + q * 4 + r) * (size_t)FST + f] = (_Float16)vr[r];
                else ((float*)outv)[(m0 + q * 4 + r) * (size_t)FST + f] = vr[r];
            }
            if (POOL) {
                // rows q*4..q*4+3 in-lane; pair q with q^1 -> 8-row group max
                float m = fmaxf(fmaxf(vr[0], vr[1]), fmaxf(vr[2], vr[3]));
                m = fmaxf(m, __shfl_xor(m, 16));
                if ((q & 1) == 0)
                    poolout[(size_t)((m0 >> 3) + (q >> 1)) * FST + f] = (_Float16)m;
            }
        }
    }
}

extern "C" void kernel_launch(void* const* d_in, const int* in_sizes, int n_in,
                              void* d_out, int out_size, void* d_ws, size_t ws_size,
                              hipStream_t stream) {
    const float* n_feat = (const float*)d_in[0];
    const int* src1 = (const int*)d_in[1];
    const int* dst1 = (const int*)d_in[2];
    const float* pkor1 = (const float*)d_in[3];
    const int* src2 = (const int*)d_in[4];
    const int* dst2 = (const int*)d_in[5];
    const float* pkor2 = (const float*)d_in[6];
    const int* src3 = (const int*)d_in[7];
    const int* dst3 = (const int*)d_in[8];
    const float* pkor3 = (const float*)d_in[9];
    const float* W1 = (const float*)d_in[16];
    const float* mu1 = (const float*)d_in[17];
    const float* is1 = (const float*)d_in[18];
    const float* b1 = (const float*)d_in[19];
    const float* W2 = (const float*)d_in[20];
    const float* mu2 = (const float*)d_in[21];
    const float* is2 = (const float*)d_in[22];
    const float* W3 = (const float*)d_in[23];
    const float* mu3 = (const float*)d_in[24];
    const float* is3 = (const float*)d_in[25];
    const float* W4 = (const float*)d_in[26];
    const float* mu4 = (const float*)d_in[27];
    const float* is4 = (const float*)d_in[28];
    const float* W5 = (const float*)d_in[29];
    const float* mu5 = (const float*)d_in[30];
    const float* is5 = (const float*)d_in[31];
    const float* b5 = (const float*)d_in[32];

    const int E1 = in_sizes[1], E2 = in_sizes[4], E3 = in_sizes[7];
    const int NT_ = N0C + N1C + N2C;

    char* w = (char*)d_ws;
    auto alloc = [&](size_t bytes) {
        void* p = (void*)w;
        w += (bytes + 255) & ~(size_t)255;
        return p;
    };
    int* degs = (int*)alloc((size_t)NT_ * 2 * 4);
    int* deg1 = degs, *deg2 = degs + N0C, *deg3 = degs + N0C + N1C;
    int* cur1 = degs + NT_, *cur2 = cur1 + N0C, *cur3 = cur2 + N1C;
    int* off1 = (int*)alloc(((size_t)N0C + 1) * 4);
    int* off2 = (int*)alloc(((size_t)N1C + 1) * 4);
    int* off3 = (int*)alloc(((size_t)N2C + 1) * 4);
    int* csrc1 = (int*)alloc((size_t)E1 * 4);
    float2* cpk1 = (float2*)alloc((size_t)E1 * 8);
    int* csrc2 = (int*)alloc((size_t)E2 * 4);
    float2* cpk2 = (float2*)alloc((size_t)E2 * 8);
    int* csrc3 = (int*)alloc((size_t)E3 * 4);
    float2* cpk3 = (float2*)alloc((size_t)E3 * 8);
    float* inv1 = (float*)alloc((size_t)N0C * 4);
    float* inv2 = (float*)alloc((size_t)N1C * 4);
    float* inv3 = (float*)alloc((size_t)N2C * 4);
    float* g1 = (float*)alloc(((size_t)2 * E1 + 2 * E2 + E3) * 12 * 4);
    float* g5 = g1 + (size_t)E1 * 12;
    float* g2 = g5 + (size_t)E1 * 12;
    float* g4 = g2 + (size_t)E2 * 12;
    float* g3 = g4 + (size_t)E2 * 12;
    _Float16* out0 = (_Float16*)alloc((size_t)N0C * 32 * 2);
    _Float16* out1 = (_Float16*)alloc((size_t)N1C * 64 * 2);
    _Float16* out2 = (_Float16*)alloc((size_t)N2C * 128 * 2);
    _Float16* out3 = (_Float16*)alloc((size_t)N1C * 64 * 2);
    _Float16* hp1 = (_Float16*)alloc((size_t)N1C * 32 * 2);
    _Float16* hp2 = (_Float16*)alloc((size_t)N2C * 64 * 2);
    _Float16* agg2 = (_Float16*)alloc((size_t)N1C * 320 * 2);
    _Float16* agg3 = (_Float16*)alloc((size_t)N2C * 640 * 2);
    _Float16* Wt2 = (_Float16*)alloc((size_t)64 * 320 * 2);
    _Float16* Wt3 = (_Float16*)alloc((size_t)128 * 640 * 2);
    _Float16* Wt4 = (_Float16*)alloc((size_t)64 * 1920 * 2);
    _Float16* Wt5 = (_Float16*)alloc((size_t)48 * 960 * 2);

    const int ET = E1 + E2 + E3;
    const int GT = 2 * E1 + 2 * E2 + E3;

    // ---- CSR build (batched) + weight prep + gw precompute
    k_prep_wt<<<cdiv(271360, 256), 256, 0, stream>>>(W1, W2, W3, W4, W5,
                                                     Wt2, Wt3, Wt4, Wt5,
                                                     degs, NT_ * 2);
    k_hist3<<<cdiv(ET, 256), 256, 0, stream>>>(dst1, dst2, dst3, deg1, deg2, deg3, E1, E2, E3);
    k_scanall<<<292, 256, 0, stream>>>(deg1, off1, inv1, deg2, off2, inv2,
                                       deg3, off3, inv3, E1, E2, E3);
    k_scatter3<<<cdiv(ET, 256), 256, 0, stream>>>(
        src1, dst1, pkor1, off1, cur1, csrc1, cpk1,
        src2, dst2, pkor2, off2, cur2, csrc2, cpk2,
        src3, dst3, pkor3, off3, cur3, csrc3, cpk3, E1, E2, E3);
    k_gw<<<cdiv(GT, 256), 256, 0, stream>>>(
        cpk1, cpk2, cpk3, mu1, is1, mu5, is5, mu2, is2, mu4, is4, mu3, is3,
        g1, g5, g2, g4, g3, E1, E2, E3);

    // ---- L1 fused: aggregate + mini-GEMM + b1 + relu -> out0; pool -> hp1
    k_l1<<<N0C * 2 / 256, 256, 0, stream>>>(n_feat, off1, csrc1, g1, inv1, W1, b1, out0, hp1);

    // ---- L2: aggX (Cin=32, ES=2) -> agg2; GEMM+relu -> out1; fused pool -> hp2
    k_aggx<8, 2><<<cdiv((size_t)N1C * 16, 256), 256, 0, stream>>>(hp1, off2, csrc2, g2, inv2, agg2, N1C);
    k_gemm2<2, 4, 10, 0, 64, 1, 1><<<dim3(1, N1C / 32), 128, 0, stream>>>(agg2, Wt2, nullptr, out1, hp2, N1C);

    // ---- L3: aggX (Cin=64, ES=4) -> agg3; GEMM+relu -> out2 (N2,128) fp16
    k_aggx<16, 4><<<cdiv((size_t)N2C * 64, 256), 256, 0, stream>>>(hp2, off3, csrc3, g3, inv3, agg3, N2C);
    k_gemm2<1, 8, 20, 0, 128, 1, 0><<<dim3(1, N2C / 16), 64, 0, stream>>>(agg3, Wt3, nullptr, out2, nullptr, N2C);

    // ---- L4 fused: aggregate + MFMA (NT=4) + relu -> out3 (N1,64) fp16
    k_aggf4<128, 64, 16, 1, 4, 0, 64, 1><<<N1C / 16, 1024, 0, stream>>>(
        out2, out1, off2, csrc2, g4, inv2, Wt4, nullptr, out3, 0);

    // ---- L5 fused: aggregate + MFMA (NT=3) + b5 + tanh -> d_out (N0,40) fp32
    k_aggf4<64, 32, 8, 2, 3, 1, 40, 0><<<N0C / 16, 512, 0, stream>>>(
        out3, out0, off1, csrc1, g5, inv1, Wt5, b5, d_out, 0);
}